// Round 1
// baseline (767.006 us; speedup 1.0000x reference)
//
#include <hip/hip_runtime.h>
#include <math.h>

namespace {
constexpr int B_ = 32, S_ = 1024, D_ = 256, N_ = 32, C_ = 64;
constexpr int NC_ = N_ * C_;    // 2048
constexpr int ROWS_ = B_ * S_;  // 32768

__device__ __forceinline__ float bflo(unsigned int u) {
  union { unsigned int i; float f; } v; v.i = u << 16; return v.f;
}
__device__ __forceinline__ float bfhi(unsigned int u) {
  union { unsigned int i; float f; } v; v.i = u & 0xffff0000u; return v.f;
}
__device__ __forceinline__ unsigned short f2bf(float f) {
  union { float f; unsigned int u; } v; v.f = f;
  unsigned int r = v.u + 0x7fffu + ((v.u >> 16) & 1u);  // RNE
  return (unsigned short)(r >> 16);
}
}  // namespace

// K1: u_hat[b,s,n,c] = sum_d x[b,s,d] * W[n,d,c], stored bf16.
// Block: 64 rows (b,s) x 64 cols (c) for one n. 256 threads, 4x4 acc/thread.
extern "C" __global__ __launch_bounds__(256) void k_gemm(
    const float* __restrict__ x, const float* __restrict__ W,
    unsigned short* __restrict__ uhat) {
  __shared__ float xs[64][68];   // [row][k]  (+4 pad: float4-aligned, conflict-free)
  __shared__ float wsh[64][68];  // [k][c]
  const int row0 = blockIdx.x * 64;
  const int n = blockIdx.y;
  const int t = threadIdx.x;
  const int tx = t & 15, ty = t >> 4;
  float acc[4][4] = {};
  const float* xb = x + (size_t)row0 * D_;
  const float* wb = W + (size_t)n * D_ * C_;

  for (int kk = 0; kk < D_; kk += 64) {
    #pragma unroll
    for (int i = 0; i < 4; ++i) {
      int v4 = t + i * 256;          // 0..1023 vec4 slots of a 64x64 tile
      int r = v4 >> 4;               // 0..63
      int c4 = (v4 & 15) << 2;       // 0..60
      *(float4*)&xs[r][c4]  = *(const float4*)&xb[r * D_ + kk + c4];
      *(float4*)&wsh[r][c4] = *(const float4*)&wb[(kk + r) * C_ + c4];
    }
    __syncthreads();
    #pragma unroll 4
    for (int k = 0; k < 64; k += 4) {
      float a_[4][4], b_[4][4];
      #pragma unroll
      for (int i = 0; i < 4; ++i) {
        float4 t4 = *(const float4*)&xs[ty * 4 + i][k];
        a_[i][0] = t4.x; a_[i][1] = t4.y; a_[i][2] = t4.z; a_[i][3] = t4.w;
      }
      #pragma unroll
      for (int q = 0; q < 4; ++q) {
        float4 t4 = *(const float4*)&wsh[k + q][tx * 4];
        b_[q][0] = t4.x; b_[q][1] = t4.y; b_[q][2] = t4.z; b_[q][3] = t4.w;
      }
      #pragma unroll
      for (int q = 0; q < 4; ++q)
        #pragma unroll
        for (int i = 0; i < 4; ++i)
          #pragma unroll
          for (int j = 0; j < 4; ++j)
            acc[i][j] += a_[i][q] * b_[q][j];
    }
    __syncthreads();
  }

  const size_t obase = (size_t)row0 * NC_ + (size_t)n * C_ + tx * 4;
  #pragma unroll
  for (int i = 0; i < 4; ++i) {
    int row = ty * 4 + i;
    ushort4 o;
    o.x = f2bf(acc[i][0]); o.y = f2bf(acc[i][1]);
    o.z = f2bf(acc[i][2]); o.w = f2bf(acc[i][3]);
    *(ushort4*)&uhat[obase + (size_t)row * NC_] = o;
  }
}

// K2: one routing pass over u_hat.
// mode 0: weights uniform 1/N (iteration 0, softmax of zeros); v, logits unused.
// mode 1: agr = u_hat.v; logits = agr; c = softmax(logits); accumulate c*u_hat.
// mode 2: same but logits += agr.
// Grid: (B, S/32). Block 256 threads: thread t owns 8 consecutive (n,c) of a
// 2048-element u_hat row -> n = t>>3. All state in registers; atomic flush.
extern "C" __global__ __launch_bounds__(256) void k_route(
    const unsigned short* __restrict__ uhat, const float* __restrict__ v,
    float* __restrict__ logits, float* __restrict__ s_out, int mode) {
  const int b = blockIdx.x;
  const int chunk = blockIdx.y;  // 32 s-rows per block
  const int t = threadIdx.x;
  __shared__ float agr[N_];
  __shared__ float cw[N_];

  float vreg[8];
  if (mode > 0) {
    float4 v0 = *(const float4*)&v[b * NC_ + t * 8];
    float4 v1 = *(const float4*)&v[b * NC_ + t * 8 + 4];
    vreg[0] = v0.x; vreg[1] = v0.y; vreg[2] = v0.z; vreg[3] = v0.w;
    vreg[4] = v1.x; vreg[5] = v1.y; vreg[6] = v1.z; vreg[7] = v1.w;
  }
  float accr[8] = {0.f, 0.f, 0.f, 0.f, 0.f, 0.f, 0.f, 0.f};

  for (int si = 0; si < 32; ++si) {
    const int s = chunk * 32 + si;
    const unsigned short* urow = uhat + (size_t)(b * S_ + s) * NC_;
    uint4 uu = *(const uint4*)(urow + t * 8);  // 8 bf16, read once
    float uf[8] = { bflo(uu.x), bfhi(uu.x), bflo(uu.y), bfhi(uu.y),
                    bflo(uu.z), bfhi(uu.z), bflo(uu.w), bfhi(uu.w) };
    float w;
    if (mode > 0) {
      float pd = 0.f;
      #pragma unroll
      for (int j = 0; j < 8; ++j) pd += uf[j] * vreg[j];
      pd += __shfl_xor(pd, 1);
      pd += __shfl_xor(pd, 2);
      pd += __shfl_xor(pd, 4);           // sum over the 8 threads of one n
      if ((t & 7) == 0) agr[t >> 3] = pd;
      __syncthreads();
      if (t < N_) {
        float l = agr[t];
        if (mode == 2) l += logits[(size_t)(b * S_ + s) * N_ + t];
        logits[(size_t)(b * S_ + s) * N_ + t] = l;
        float mx = l;
        #pragma unroll
        for (int m = 16; m; m >>= 1) mx = fmaxf(mx, __shfl_xor(mx, m));
        float e = expf(l - mx);
        float se = e;
        #pragma unroll
        for (int m = 16; m; m >>= 1) se += __shfl_xor(se, m);
        cw[t] = e / se;
      }
      __syncthreads();
      w = cw[t >> 3];
    } else {
      w = 1.0f / N_;
    }
    #pragma unroll
    for (int j = 0; j < 8; ++j) accr[j] += w * uf[j];
  }
  #pragma unroll
  for (int j = 0; j < 8; ++j)
    atomicAdd(&s_out[b * NC_ + t * 8 + j], accr[j]);
}

// K3: squash along C. One block per (b,n), 64 threads.
extern "C" __global__ __launch_bounds__(64) void k_squash(
    const float* __restrict__ s_in, float* __restrict__ v_out) {
  const int bn = blockIdx.x;
  const int lane = threadIdx.x;
  float val = s_in[bn * C_ + lane];
  float sq = val * val;
  #pragma unroll
  for (int m = 32; m; m >>= 1) sq += __shfl_xor(sq, m);
  float scale = sq / ((1.f + sq) * sqrtf(sq + 1e-8f));
  v_out[bn * C_ + lane] = val * scale;
}

extern "C" void kernel_launch(void* const* d_in, const int* in_sizes, int n_in,
                              void* d_out, int out_size, void* d_ws, size_t ws_size,
                              hipStream_t stream) {
  const float* x = (const float*)d_in[0];   // [B,S,D]
  const float* W = (const float*)d_in[1];   // [N,D,C]
  float* out = (float*)d_out;               // [B,N,C]

  // Workspace layout (needs ~139 MB):
  unsigned short* uhat = (unsigned short*)d_ws;                  // 134,217,728 B
  float* logits = (float*)((char*)d_ws + (size_t)ROWS_ * NC_ * 2);  // 4 MB
  float* sbuf = logits + (size_t)B_ * S_ * N_;                   // 256 KB
  float* vbuf = sbuf + B_ * NC_;                                 // 256 KB

  // 1) u_hat GEMM (bf16 store)
  k_gemm<<<dim3(ROWS_ / 64, N_), 256, 0, stream>>>(x, W, uhat);

  // 2) iter 0: s1 = (1/N) sum_s u_hat
  hipMemsetAsync(sbuf, 0, (size_t)B_ * NC_ * sizeof(float), stream);
  k_route<<<dim3(B_, S_ / 32), 256, 0, stream>>>(uhat, vbuf, logits, sbuf, 0);
  k_squash<<<B_ * N_, 64, 0, stream>>>(sbuf, vbuf);

  // 3) iter 1: agr1 -> logits=agr1 -> c2 -> s2
  hipMemsetAsync(sbuf, 0, (size_t)B_ * NC_ * sizeof(float), stream);
  k_route<<<dim3(B_, S_ / 32), 256, 0, stream>>>(uhat, vbuf, logits, sbuf, 1);
  k_squash<<<B_ * N_, 64, 0, stream>>>(sbuf, vbuf);

  // 4) iter 2: agr2 -> logits+=agr2 -> c3 -> s3 -> v (output)
  hipMemsetAsync(sbuf, 0, (size_t)B_ * NC_ * sizeof(float), stream);
  k_route<<<dim3(B_, S_ / 32), 256, 0, stream>>>(uhat, vbuf, logits, sbuf, 2);
  k_squash<<<B_ * N_, 64, 0, stream>>>(sbuf, out);
}

// Round 2
// 232.715 us; speedup vs baseline: 3.2959x; 3.2959x over previous
//
#include <hip/hip_runtime.h>
#include <math.h>

namespace {
constexpr int B_ = 32, S_ = 1024, D_ = 256, N_ = 32, C_ = 64;
constexpr int NC_ = N_ * C_;    // 2048
constexpr int ROWS_ = B_ * S_;  // 32768

typedef __bf16 bf16x8 __attribute__((ext_vector_type(8)));
typedef float floatx4 __attribute__((ext_vector_type(4)));

__device__ __forceinline__ float bflo(unsigned int u) {
  union { unsigned int i; float f; } v; v.i = u << 16; return v.f;
}
__device__ __forceinline__ float bfhi(unsigned int u) {
  union { unsigned int i; float f; } v; v.i = u & 0xffff0000u; return v.f;
}
__device__ __forceinline__ void async16(const void* g, void* l) {
  __builtin_amdgcn_global_load_lds(
      (const __attribute__((address_space(1))) void*)g,
      (__attribute__((address_space(3))) void*)l, 16, 0, 0);
}
__device__ __forceinline__ void unpack8(uint4 u, float* o) {
  o[0] = bflo(u.x); o[1] = bfhi(u.x); o[2] = bflo(u.y); o[3] = bfhi(u.y);
  o[4] = bflo(u.z); o[5] = bfhi(u.z); o[6] = bflo(u.w); o[7] = bfhi(u.w);
}
}  // namespace

// K0: Wt[n][c][d] = bf16(W[n][d][c])  (B^T layout, k contiguous)
extern "C" __global__ __launch_bounds__(256) void k_convW(
    const float* __restrict__ W, __bf16* __restrict__ Wt) {
  const int n = blockIdx.x, d0 = blockIdx.y * 64;
  __shared__ float tile[64][65];
  const int t = threadIdx.x;
  #pragma unroll
  for (int i = 0; i < 16; ++i) {
    int e = i * 256 + t;
    int dd = e >> 6, c = e & 63;
    tile[dd][c] = W[(size_t)n * (D_ * C_) + (size_t)(d0 + dd) * C_ + c];
  }
  __syncthreads();
  #pragma unroll
  for (int i = 0; i < 16; ++i) {
    int e = i * 256 + t;
    int c = e >> 6, dd = e & 63;
    Wt[(size_t)(n * 64 + c) * D_ + d0 + dd] = (__bf16)tile[dd][c];
  }
}

// K1: u_hat = x @ W  (bf16 MFMA), 128x128 tile, BK=64, fused s1-partial.
// LDS chunk swizzle: content (row, kcg) stored at linear chunk row*8 + (kcg^(row&7)).
extern "C" __global__ __launch_bounds__(256) void k_gemm(
    const float* __restrict__ x, const __bf16* __restrict__ Wt,
    __bf16* __restrict__ uhat, float* __restrict__ sbuf) {
  __shared__ __align__(16) __bf16 As[128 * 64];
  __shared__ __align__(16) __bf16 Bs[128 * 64];
  __shared__ float sred[2][128];
  const int t = threadIdx.x;
  const int col0 = blockIdx.x * 128;
  const int row0 = blockIdx.y * 128;
  const int w = t >> 6, lane = t & 63, quad = lane >> 4, l16 = lane & 15;
  const int rw0 = (w & 1) * 64, cw0 = (w >> 1) * 64;

  const float* gA[4];
  const __bf16* gB[4];
  __bf16* lA[4];
  __bf16* lB[4];
  #pragma unroll
  for (int i = 0; i < 4; ++i) {
    int L = i * 256 + t;
    int r = L >> 3, kcl = L & 7, kcg = kcl ^ (r & 7);
    gA[i] = x + (size_t)(row0 + r) * D_ + kcg * 8;
    gB[i] = Wt + (size_t)(col0 + r) * D_ + kcg * 8;
    lA[i] = As + L * 8;
    lB[i] = Bs + L * 8;
  }
  int aoff[4][2], boff[4][2];
  #pragma unroll
  for (int i = 0; i < 4; ++i) {
    int m = rw0 + i * 16 + l16;
    int c = cw0 + i * 16 + l16;
    #pragma unroll
    for (int ks = 0; ks < 2; ++ks) {
      int kcg = ks * 4 + quad;
      aoff[i][ks] = (m * 8 + (kcg ^ (m & 7))) * 8;
      boff[i][ks] = (c * 8 + (kcg ^ (c & 7))) * 8;
    }
  }

  floatx4 acc[4][4];
  #pragma unroll
  for (int i = 0; i < 4; ++i)
    #pragma unroll
    for (int j = 0; j < 4; ++j)
      acc[i][j] = (floatx4){0.f, 0.f, 0.f, 0.f};

  for (int kk = 0; kk < D_; kk += 64) {
    #pragma unroll
    for (int i = 0; i < 4; ++i) async16(gB[i] + kk, lB[i]);  // B: async DMA
    #pragma unroll
    for (int i = 0; i < 4; ++i) {                            // A: load+cvt+write
      float4 f0 = *(const float4*)(gA[i] + kk);
      float4 f1 = *(const float4*)(gA[i] + kk + 4);
      bf16x8 p;
      p[0] = (__bf16)f0.x; p[1] = (__bf16)f0.y; p[2] = (__bf16)f0.z; p[3] = (__bf16)f0.w;
      p[4] = (__bf16)f1.x; p[5] = (__bf16)f1.y; p[6] = (__bf16)f1.z; p[7] = (__bf16)f1.w;
      *(bf16x8*)lA[i] = p;
    }
    __syncthreads();
    #pragma unroll
    for (int ks = 0; ks < 2; ++ks) {
      bf16x8 af[4], bfr[4];
      #pragma unroll
      for (int i = 0; i < 4; ++i) af[i] = *(const bf16x8*)(As + aoff[i][ks]);
      #pragma unroll
      for (int j = 0; j < 4; ++j) bfr[j] = *(const bf16x8*)(Bs + boff[j][ks]);
      #pragma unroll
      for (int i = 0; i < 4; ++i)
        #pragma unroll
        for (int j = 0; j < 4; ++j)
          acc[i][j] = __builtin_amdgcn_mfma_f32_16x16x32_bf16(af[i], bfr[j], acc[i][j], 0, 0, 0);
    }
    __syncthreads();
  }

  // Epilogue: u_hat store (bf16) + fused s1 column-sum partial.
  const int b_idx = row0 >> 10;
  #pragma unroll
  for (int j = 0; j < 4; ++j) {
    float cs = 0.f;
    const int col_g = col0 + cw0 + j * 16 + l16;
    #pragma unroll
    for (int i = 0; i < 4; ++i) {
      const int row_g = row0 + rw0 + i * 16 + quad * 4;
      #pragma unroll
      for (int r = 0; r < 4; ++r) {
        float vv = acc[i][j][r];
        cs += vv;
        uhat[(size_t)(row_g + r) * NC_ + col_g] = (__bf16)vv;
      }
    }
    cs += __shfl_xor(cs, 16);
    cs += __shfl_xor(cs, 32);
    if (lane < 16) sred[w & 1][cw0 + j * 16 + l16] = cs;
  }
  __syncthreads();
  if (t < 128) {
    float ssum = (sred[0][t] + sred[1][t]) * (1.0f / 32.0f);
    atomicAdd(&sbuf[b_idx * NC_ + col0 + t], ssum);
  }
}

// K2: one routing pass. Wave-independent: each wave owns whole s-rows.
// Lane l covers n = l>>1, c-half = l&1 -> 32 contiguous elems = lane*32.
// add_logits=0: logits = agr; add_logits=1: logits += agr. c = softmax; acc c*u_hat.
extern "C" __global__ __launch_bounds__(256) void k_route(
    const unsigned short* __restrict__ uhat, const float* __restrict__ v,
    float* __restrict__ logits, float* __restrict__ s_out, int add_logits) {
  const int b = blockIdx.x, chunk = blockIdx.y;
  const int t = threadIdx.x, w = t >> 6, lane = t & 63;
  const int n = lane >> 1;
  __shared__ float red[4][NC_];

  float vreg[32];
  #pragma unroll
  for (int q = 0; q < 8; ++q) {
    float4 f = *(const float4*)&v[b * NC_ + lane * 32 + q * 4];
    vreg[q * 4 + 0] = f.x; vreg[q * 4 + 1] = f.y;
    vreg[q * 4 + 2] = f.z; vreg[q * 4 + 3] = f.w;
  }
  float accr[32];
  #pragma unroll
  for (int j = 0; j < 32; ++j) accr[j] = 0.f;

  for (int si = 0; si < 8; ++si) {
    const int s = chunk * 32 + w * 8 + si;
    const size_t base = (size_t)(b * S_ + s) * NC_ + lane * 32;
    uint4 u0 = *(const uint4*)(uhat + base);
    uint4 u1 = *(const uint4*)(uhat + base + 8);
    uint4 u2 = *(const uint4*)(uhat + base + 16);
    uint4 u3 = *(const uint4*)(uhat + base + 24);
    float uf[32];
    unpack8(u0, uf); unpack8(u1, uf + 8); unpack8(u2, uf + 16); unpack8(u3, uf + 24);
    float pd = 0.f;
    #pragma unroll
    for (int j = 0; j < 32; ++j) pd += uf[j] * vreg[j];
    pd += __shfl_xor(pd, 1);  // full 64-c agreement for this n
    const size_t lidx = (size_t)(b * S_ + s) * N_ + n;
    float lg = pd;
    if (add_logits) lg += logits[lidx];
    if ((lane & 1) == 0) logits[lidx] = lg;
    float mx = lg;
    #pragma unroll
    for (int m = 2; m <= 32; m <<= 1) mx = fmaxf(mx, __shfl_xor(mx, m));
    float e = __expf(lg - mx);
    float se = e;
    #pragma unroll
    for (int m = 2; m <= 32; m <<= 1) se += __shfl_xor(se, m);
    float wgt = e / se;
    #pragma unroll
    for (int j = 0; j < 32; ++j) accr[j] += wgt * uf[j];
  }
  #pragma unroll
  for (int q = 0; q < 8; ++q) {
    float4 f;
    f.x = accr[q * 4]; f.y = accr[q * 4 + 1];
    f.z = accr[q * 4 + 2]; f.w = accr[q * 4 + 3];
    *(float4*)&red[w][lane * 32 + q * 4] = f;
  }
  __syncthreads();
  #pragma unroll
  for (int q = 0; q < 8; ++q) {
    int f = q * 256 + t;
    float sv = red[0][f] + red[1][f] + red[2][f] + red[3][f];
    atomicAdd(&s_out[b * NC_ + f], sv);
  }
}

// K3: squash along C. One block per (b,n), 64 threads.
extern "C" __global__ __launch_bounds__(64) void k_squash(
    const float* __restrict__ s_in, float* __restrict__ v_out) {
  const int bn = blockIdx.x;
  const int lane = threadIdx.x;
  float val = s_in[bn * C_ + lane];
  float sq = val * val;
  #pragma unroll
  for (int m = 32; m; m >>= 1) sq += __shfl_xor(sq, m);
  float scale = sq / ((1.f + sq) * sqrtf(sq + 1e-8f));
  v_out[bn * C_ + lane] = val * scale;
}

extern "C" void kernel_launch(void* const* d_in, const int* in_sizes, int n_in,
                              void* d_out, int out_size, void* d_ws, size_t ws_size,
                              hipStream_t stream) {
  const float* x = (const float*)d_in[0];   // [B,S,D]
  const float* W = (const float*)d_in[1];   // [N,D,C]
  float* out = (float*)d_out;               // [B,N,C]

  // Workspace layout (~133.5 MiB total):
  char* ws = (char*)d_ws;
  __bf16* uhat = (__bf16*)ws;                                  // 134,217,728 B
  __bf16* Wt = (__bf16*)(ws + (size_t)ROWS_ * NC_ * 2);        // 1,048,576 B
  float* logits = (float*)(ws + (size_t)ROWS_ * NC_ * 2 + (size_t)N_ * D_ * C_ * 2);
  float* sbuf = logits + (size_t)B_ * S_ * N_;                 // 262,144 B
  float* vbuf = sbuf + B_ * NC_;                               // 262,144 B

  // 0) W -> Wt (bf16, [n][c][d])
  k_convW<<<dim3(N_, 4), 256, 0, stream>>>(W, Wt);

  // 1) GEMM + fused iter-0 s-sum; squash -> v1
  hipMemsetAsync(sbuf, 0, (size_t)B_ * NC_ * sizeof(float), stream);
  k_gemm<<<dim3(NC_ / 128, ROWS_ / 128), 256, 0, stream>>>(x, Wt, uhat, sbuf);
  k_squash<<<B_ * N_, 64, 0, stream>>>(sbuf, vbuf);

  // 2) iter 1: logits = agr(v1); c2 = softmax; s2; squash -> v2
  hipMemsetAsync(sbuf, 0, (size_t)B_ * NC_ * sizeof(float), stream);
  k_route<<<dim3(B_, S_ / 32), 256, 0, stream>>>((const unsigned short*)uhat,
                                                 vbuf, logits, sbuf, 0);
  k_squash<<<B_ * N_, 64, 0, stream>>>(sbuf, vbuf);

  // 3) iter 2: logits += agr(v2); c3 = softmax; s3; squash -> out
  hipMemsetAsync(sbuf, 0, (size_t)B_ * NC_ * sizeof(float), stream);
  k_route<<<dim3(B_, S_ / 32), 256, 0, stream>>>((const unsigned short*)uhat,
                                                 vbuf, logits, sbuf, 1);
  k_squash<<<B_ * N_, 64, 0, stream>>>(sbuf, out);
}